// Round 1
// baseline (8410.323 us; speedup 1.0000x reference)
//
#include <hip/hip_runtime.h>

#define DD 128
#define TT 16
#define BR 16
#define PAD 132   // padded LDS row stride: breaks 4-way bank conflict on ins[r][k] broadcast reads

// out[c0..c0+7] = bias[c0..] + sum_k ins[r][k] * W[k][c0..]; W row-major [128][128]
template<bool RELU_IN>
__device__ __forceinline__ void mm128(const float (&ins)[BR][PAD], int r, int c0,
                                      const float* __restrict__ W,
                                      const float* __restrict__ bias,
                                      float acc[8])
{
#pragma unroll
    for (int u = 0; u < 8; ++u) acc[u] = bias[c0 + u];
#pragma unroll 4
    for (int k4 = 0; k4 < 32; ++k4) {
        float4 a4 = *reinterpret_cast<const float4*>(&ins[r][4 * k4]);
        if (RELU_IN) {
            a4.x = fmaxf(a4.x, 0.f); a4.y = fmaxf(a4.y, 0.f);
            a4.z = fmaxf(a4.z, 0.f); a4.w = fmaxf(a4.w, 0.f);
        }
        const float av[4] = {a4.x, a4.y, a4.z, a4.w};
#pragma unroll
        for (int t = 0; t < 4; ++t) {
            const float* wr = W + (size_t)(4 * k4 + t) * DD + c0;
            const float4 w0 = *reinterpret_cast<const float4*>(wr);
            const float4 w1 = *reinterpret_cast<const float4*>(wr + 4);
            const float a = av[t];
            acc[0] = fmaf(a, w0.x, acc[0]);
            acc[1] = fmaf(a, w0.y, acc[1]);
            acc[2] = fmaf(a, w0.z, acc[2]);
            acc[3] = fmaf(a, w0.w, acc[3]);
            acc[4] = fmaf(a, w1.x, acc[4]);
            acc[5] = fmaf(a, w1.y, acc[5]);
            acc[6] = fmaf(a, w1.z, acc[6]);
            acc[7] = fmaf(a, w1.w, acc[7]);
        }
    }
}

// single output column i of [1,128] @ [128,16]
template<bool RELU_IN>
__device__ __forceinline__ float mmN16(const float (&ins)[BR][PAD], int r, int i,
                                       const float* __restrict__ W,
                                       const float* __restrict__ bias)
{
    float acc = bias[i];
#pragma unroll 8
    for (int k4 = 0; k4 < 32; ++k4) {
        float4 a4 = *reinterpret_cast<const float4*>(&ins[r][4 * k4]);
        if (RELU_IN) {
            a4.x = fmaxf(a4.x, 0.f); a4.y = fmaxf(a4.y, 0.f);
            a4.z = fmaxf(a4.z, 0.f); a4.w = fmaxf(a4.w, 0.f);
        }
        acc = fmaf(a4.x, W[(size_t)(4 * k4 + 0) * TT + i], acc);
        acc = fmaf(a4.y, W[(size_t)(4 * k4 + 1) * TT + i], acc);
        acc = fmaf(a4.z, W[(size_t)(4 * k4 + 2) * TT + i], acc);
        acc = fmaf(a4.w, W[(size_t)(4 * k4 + 3) * TT + i], acc);
    }
    return acc;
}

// out[c0..c0+7] = bias + sum_k relu(fl[k]) * W[k][c0..]; K in {16,32,48}
__device__ __forceinline__ void mmSmall(const float* fl, int K, int c0,
                                        const float* __restrict__ W,
                                        const float* __restrict__ bias,
                                        float acc[8])
{
#pragma unroll
    for (int u = 0; u < 8; ++u) acc[u] = bias[c0 + u];
    for (int k = 0; k < K; ++k) {
        const float a = fmaxf(fl[k], 0.f);
        const float* wr = W + (size_t)k * DD + c0;
        const float4 w0 = *reinterpret_cast<const float4*>(wr);
        const float4 w1 = *reinterpret_cast<const float4*>(wr + 4);
        acc[0] = fmaf(a, w0.x, acc[0]);
        acc[1] = fmaf(a, w0.y, acc[1]);
        acc[2] = fmaf(a, w0.z, acc[2]);
        acc[3] = fmaf(a, w0.w, acc[3]);
        acc[4] = fmaf(a, w1.x, acc[4]);
        acc[5] = fmaf(a, w1.y, acc[5]);
        acc[6] = fmaf(a, w1.z, acc[6]);
        acc[7] = fmaf(a, w1.w, acc[7]);
    }
}

__global__ void __launch_bounds__(256)
softmod_fused(const float* __restrict__ x,
              const int* __restrict__ task_id_p,
              const float* __restrict__ teW, const float* __restrict__ teB,
              const float* __restrict__ gfW, const float* __restrict__ gfB,
              const float* __restrict__ gw0W, const float* __restrict__ gw0B,
              const float* __restrict__ c1W,  const float* __restrict__ c1B,
              const float* __restrict__ gw1W, const float* __restrict__ gw1B,
              const float* __restrict__ c2W,  const float* __restrict__ c2B,
              const float* __restrict__ gw2W, const float* __restrict__ gw2B,
              const float* __restrict__ cLW,  const float* __restrict__ cLB,
              const float* __restrict__ lfW,  const float* __restrict__ lfB,
              const float* __restrict__ bW,   const float* __restrict__ bB,
              float* __restrict__ out)
{
    __shared__ float xs[BR][PAD];      // raw x rows
    __shared__ float embs[BR][PAD];    // emb (post gating_fc, NOT relu'd)
    __shared__ float vs[BR][PAD];      // generic staging (e0 / cond / inp_j)
    __shared__ float flat_s[BR][3][TT];// [sm0, raw1, raw2] contiguous per row
    __shared__ float sm_s[BR][3][TT];  // softmaxed routing weights
    __shared__ float lraw[BR][4];
    __shared__ float lw[BR][4];
    __shared__ float embC[DD];

    const int tid = threadIdx.x;
    const int r  = tid >> 4;       // local row 0..15
    const int ci = tid & 15;       // col team 0..15
    const int c0 = ci * 8;         // 8 consecutive cols per thread
    const long long row = (long long)blockIdx.x * BR + r;

    // P0: embC = task_embed_W[task_id] + task_embed_b ; load x rows
    if (tid < DD) {
        const int tsk = *task_id_p;
        embC[tid] = teW[(size_t)tsk * DD + tid] + teB[tid];
    }
    {
        const float4* xg = reinterpret_cast<const float4*>(x + row * DD + c0);
        const float4 a = xg[0], b = xg[1];
        *reinterpret_cast<float4*>(&xs[r][c0])     = a;
        *reinterpret_cast<float4*>(&xs[r][c0 + 4]) = b;
    }
    __syncthreads();

    // P2: e0 = relu(embC * x) -> vs   (relu(relu(y)) == relu(y))
#pragma unroll
    for (int u = 0; u < 8; ++u)
        vs[r][c0 + u] = fmaxf(embC[c0 + u] * xs[r][c0 + u], 0.f);
    __syncthreads();

    // P3: emb = e0 @ gating_fc_W + b -> embs (no output relu)
    {
        float acc[8];
        mm128<false>(vs, r, c0, gfW, gfB, acc);
#pragma unroll
        for (int u = 0; u < 8; ++u) embs[r][c0 + u] = acc[u];
    }
    __syncthreads();

    // P4: raw0 = relu(emb) @ gw_fc0_W + b -> vs[r][0..15]
    vs[r][ci] = mmN16<true>(embs, r, ci, gw0W, gw0B);
    __syncthreads();

    // P5: softmax over groups of 4 -> sm_s[r][0], flat_s[r][0]
    {
        const int gb = ci & ~3;
        const float v0 = vs[r][gb], v1 = vs[r][gb + 1], v2 = vs[r][gb + 2], v3 = vs[r][gb + 3];
        const float mx = fmaxf(fmaxf(v0, v1), fmaxf(v2, v3));
        const float s = expf(v0 - mx) + expf(v1 - mx) + expf(v2 - mx) + expf(v3 - mx);
        const float val = expf(vs[r][ci] - mx) / s;
        sm_s[r][0][ci] = val;
        flat_s[r][0][ci] = val;
    }
    __syncthreads();

    // P6: cond1 = relu(flat0) @ cond_fc1_W + b ; relu(cond1*emb) -> vs
    {
        float acc[8];
        mmSmall(&flat_s[r][0][0], 16, c0, c1W, c1B, acc);
#pragma unroll
        for (int u = 0; u < 8; ++u)
            vs[r][c0 + u] = fmaxf(acc[u] * embs[r][c0 + u], 0.f);
    }
    __syncthreads();

    // P7: raw1 = cond1 @ gw_fc1_W + b -> flat_s[r][1] (raw, un-softmaxed)
    flat_s[r][1][ci] = mmN16<false>(vs, r, ci, gw1W, gw1B);
    __syncthreads();

    // P8: softmax(raw1) -> sm_s[r][1]
    {
        const int gb = ci & ~3;
        const float* fr = &flat_s[r][1][0];
        const float v0 = fr[gb], v1 = fr[gb + 1], v2 = fr[gb + 2], v3 = fr[gb + 3];
        const float mx = fmaxf(fmaxf(v0, v1), fmaxf(v2, v3));
        const float s = expf(v0 - mx) + expf(v1 - mx) + expf(v2 - mx) + expf(v3 - mx);
        sm_s[r][1][ci] = expf(fr[ci] - mx) / s;
    }
    __syncthreads();

    // P9: cond2 = relu(concat(flat0,flat1)) @ cond_fc2_W + b ; relu(*emb) -> vs
    {
        float acc[8];
        mmSmall(&flat_s[r][0][0], 32, c0, c2W, c2B, acc);
#pragma unroll
        for (int u = 0; u < 8; ++u)
            vs[r][c0 + u] = fmaxf(acc[u] * embs[r][c0 + u], 0.f);
    }
    __syncthreads();

    // P10: raw2 -> flat_s[r][2]
    flat_s[r][2][ci] = mmN16<false>(vs, r, ci, gw2W, gw2B);
    __syncthreads();
    {
        const int gb = ci & ~3;
        const float* fr = &flat_s[r][2][0];
        const float v0 = fr[gb], v1 = fr[gb + 1], v2 = fr[gb + 2], v3 = fr[gb + 3];
        const float mx = fmaxf(fmaxf(v0, v1), fmaxf(v2, v3));
        const float s = expf(v0 - mx) + expf(v1 - mx) + expf(v2 - mx) + expf(v3 - mx);
        sm_s[r][2][ci] = expf(fr[ci] - mx) / s;
    }
    __syncthreads();

    // P11: condL = relu(concat(48)) @ cond_last_W + b ; relu(*emb) -> vs
    {
        float acc[8];
        mmSmall(&flat_s[r][0][0], 48, c0, cLW, cLB, acc);
#pragma unroll
        for (int u = 0; u < 8; ++u)
            vs[r][c0 + u] = fmaxf(acc[u] * embs[r][c0 + u], 0.f);
    }
    __syncthreads();

    // P12: last_w = softmax(condL @ last_fc_W + b) over 4 modules
    if (ci < 4) {
        float acc = lfB[ci];
        for (int k = 0; k < DD; ++k)
            acc = fmaf(vs[r][k], lfW[(size_t)k * 4 + ci], acc);
        lraw[r][ci] = acc;
    }
    __syncthreads();
    if (ci < 4) {
        const float v0 = lraw[r][0], v1 = lraw[r][1], v2 = lraw[r][2], v3 = lraw[r][3];
        const float mx = fmaxf(fmaxf(v0, v1), fmaxf(v2, v3));
        const float s = expf(v0 - mx) + expf(v1 - mx) + expf(v2 - mx) + expf(v3 - mx);
        lw[r][ci] = expf(lraw[r][ci] - mx) / s;
    }
    __syncthreads();

    // P13: base layer 0: mid[m] = x @ base_W[0][m] + base_b[0][m]
    float mid[4][8];
#pragma unroll
    for (int m = 0; m < 4; ++m)
        mm128<false>(xs, r, c0, bW + (size_t)m * DD * DD, bB + (size_t)m * DD, mid[m]);

    // P14: layers 1..3: inp[j] = relu(sum_m mid[m]*w[j,m]); mid[j] = inp[j] @ W[l][j] + b
#pragma unroll
    for (int i = 0; i < 3; ++i) {
        float inp[4][8];
#pragma unroll
        for (int j = 0; j < 4; ++j) {
            const float w0 = sm_s[r][i][j * 4 + 0];
            const float w1 = sm_s[r][i][j * 4 + 1];
            const float w2 = sm_s[r][i][j * 4 + 2];
            const float w3 = sm_s[r][i][j * 4 + 3];
#pragma unroll
            for (int u = 0; u < 8; ++u)
                inp[j][u] = fmaxf(mid[0][u] * w0 + mid[1][u] * w1 +
                                  mid[2][u] * w2 + mid[3][u] * w3, 0.f);
        }
#pragma unroll
        for (int j = 0; j < 4; ++j) {
            __syncthreads();   // previous vs readers done
#pragma unroll
            for (int u = 0; u < 8; ++u) vs[r][c0 + u] = inp[j][u];
            __syncthreads();
            mm128<false>(vs, r, c0, bW + (size_t)((i + 1) * 4 + j) * DD * DD,
                         bB + (size_t)((i + 1) * 4 + j) * DD, mid[j]);
        }
    }

    // P15: out = sum_j mid[j] * last_w[j]
    {
        const float l0 = lw[r][0], l1 = lw[r][1], l2 = lw[r][2], l3 = lw[r][3];
        float o[8];
#pragma unroll
        for (int u = 0; u < 8; ++u)
            o[u] = mid[0][u] * l0 + mid[1][u] * l1 + mid[2][u] * l2 + mid[3][u] * l3;
        float4* og = reinterpret_cast<float4*>(out + row * DD + c0);
        og[0] = make_float4(o[0], o[1], o[2], o[3]);
        og[1] = make_float4(o[4], o[5], o[6], o[7]);
    }
}

extern "C" void kernel_launch(void* const* d_in, const int* in_sizes, int n_in,
                              void* d_out, int out_size, void* d_ws, size_t ws_size,
                              hipStream_t stream) {
    const float* x    = (const float*)d_in[0];
    const int*   tsk  = (const int*)  d_in[1];
    const float* teW  = (const float*)d_in[2];
    const float* teB  = (const float*)d_in[3];
    const float* gfW  = (const float*)d_in[4];
    const float* gfB  = (const float*)d_in[5];
    const float* gw0W = (const float*)d_in[6];
    const float* gw0B = (const float*)d_in[7];
    const float* c1W  = (const float*)d_in[8];
    const float* c1B  = (const float*)d_in[9];
    const float* gw1W = (const float*)d_in[10];
    const float* gw1B = (const float*)d_in[11];
    const float* c2W  = (const float*)d_in[12];
    const float* c2B  = (const float*)d_in[13];
    const float* gw2W = (const float*)d_in[14];
    const float* gw2B = (const float*)d_in[15];
    const float* cLW  = (const float*)d_in[16];
    const float* cLB  = (const float*)d_in[17];
    const float* lfW  = (const float*)d_in[18];
    const float* lfB  = (const float*)d_in[19];
    const float* bW   = (const float*)d_in[20];
    const float* bB   = (const float*)d_in[21];
    float* out = (float*)d_out;

    const int Bn = in_sizes[0] / DD;          // 262144
    const int grid = Bn / BR;                 // 16384 blocks, exact

    softmod_fused<<<grid, 256, 0, stream>>>(x, tsk, teW, teB, gfW, gfB,
                                            gw0W, gw0B, c1W, c1B, gw1W, gw1B,
                                            c2W, c2B, gw2W, gw2B, cLW, cLB,
                                            lfW, lfB, bW, bB, out);
}

// Round 4
// 1971.450 us; speedup vs baseline: 4.2661x; 4.2661x over previous
//
#include <hip/hip_runtime.h>

typedef unsigned int   u32;
typedef unsigned short u16;
typedef __attribute__((ext_vector_type(8))) short short8;  // bf16x8 MFMA frag (4 VGPR)
typedef __attribute__((ext_vector_type(4))) float f32x4;
typedef __attribute__((ext_vector_type(4))) u32   u32x4;

#define NMAT 17      // 1 gating + 16 base matrices
#define PBS  132     // pair-buffer row stride (u32 / f32 units): 132%32=4 -> <=2-way bank alias
#define FLS  52      // flats row stride (f32)

union FragU { u32x4 u; short8 s; };

// split 8 fp32 -> hi bf16x8 (truncated) + lo bf16x8 (rounded); v ~= hi + lo to ~2^-17 rel
__device__ __forceinline__ void split8(const float v[8], short8& H, short8& L) {
    u32 hb[8], lb[8];
#pragma unroll
    for (int i = 0; i < 8; ++i) {
        const u32 u = __float_as_uint(v[i]);
        hb[i] = u & 0xFFFF0000u;
        lb[i] = __float_as_uint(v[i] - __uint_as_float(hb[i])) + 0x8000u;
    }
    FragU h, l;
#pragma unroll
    for (int j = 0; j < 4; ++j) {
        h.u[j] = (hb[2*j] >> 16) | hb[2*j+1];                  // low16 = even k
        l.u[j] = (lb[2*j] >> 16) | (lb[2*j+1] & 0xFFFF0000u);
    }
    H = h.s; L = l.s;
}

// ---------------- prep: fp32 weights -> split-bf16 MFMA B-fragment planes in ws ----------------
// plane pp = (mat*4+ks)*8 + t  (t = N-tile 0..7): u16[1024]; [0..511]=hi (lane*8+i), [512..1023]=lo
extern "C" __global__ void prep_weights(const float* __restrict__ gfW,
                                        const float* __restrict__ bW,
                                        u16* __restrict__ wsB)
{
    const int id = blockIdx.x * 256 + threadIdx.x;
    if (id >= NMAT * 4 * 8 * 64) return;
    const int lane = id & 63;
    const int t    = (id >> 6) & 7;
    const int ks   = (id >> 9) & 3;
    const int mat  = id >> 11;
    const float* W = (mat == 0) ? gfW : (bW + (size_t)(mat - 1) * 16384);
    const int n  = t * 16 + (lane & 15);          // B col
    const int kb = ks * 32 + (lane >> 4) * 8;     // 8 contiguous k per lane-group
    u32 hb[8], lb[8];
#pragma unroll
    for (int i = 0; i < 8; ++i) {
        const float v = W[(size_t)(kb + i) * 128 + n];
        const u32 u = __float_as_uint(v);
        hb[i] = u & 0xFFFF0000u;
        lb[i] = __float_as_uint(v - __uint_as_float(hb[i])) + 0x8000u;
    }
    FragU H, L;
#pragma unroll
    for (int j = 0; j < 4; ++j) {
        H.u[j] = (hb[2*j] >> 16) | hb[2*j+1];
        L.u[j] = (lb[2*j] >> 16) | (lb[2*j+1] & 0xFFFF0000u);
    }
    u16* p = wsB + (size_t)(((mat * 4 + ks) * 8 + t) * 1024) + lane * 8;
    *reinterpret_cast<u32x4*>(p)       = H.u;
    *reinterpret_cast<u32x4*>(p + 512) = L.u;
}

// ---------------- main fused kernel: 512 thr = 8 waves, 64 rows/block, 1 N-tile/wave ----------------
extern "C" __global__ void __launch_bounds__(512, 2)
softmod_mfma(const float* __restrict__ x, const int* __restrict__ task_id_p,
             const float* __restrict__ teW, const float* __restrict__ teB,
             const float* __restrict__ gfB,
             const float* __restrict__ gw0W, const float* __restrict__ gw0B,
             const float* __restrict__ c1W,  const float* __restrict__ c1B,
             const float* __restrict__ gw1W, const float* __restrict__ gw1B,
             const float* __restrict__ c2W,  const float* __restrict__ c2B,
             const float* __restrict__ gw2W, const float* __restrict__ gw2B,
             const float* __restrict__ cLW,  const float* __restrict__ cLB,
             const float* __restrict__ lfW,  const float* __restrict__ lfB,
             const float* __restrict__ bB,
             const u16* __restrict__ wsB,
             float* __restrict__ out)
{
    __shared__ u32   pairBuf[2][64 * PBS];   // 67,584 B: mix buffers; aliased by routing f32 bufs
    __shared__ float smT[3][16][64];         // softmax routing weights, [layer][j*4+m][row]
    __shared__ float lwT[4][64];             // last_w, [j][row]
    __shared__ float flS[64][FLS];           // flats (fp32): [sm0 | raw1 | raw2]
    __shared__ float embC[128];              // task embedding + bias

    float* embsF = reinterpret_cast<float*>(&pairBuf[0][0]);  // [64][PBS] fp32 emb (routing)
    float* vsF   = reinterpret_cast<float*>(&pairBuf[1][0]);  // [64][PBS] fp32 cond staging

    const int tid  = threadIdx.x;
    const int lane = tid & 63;
    const int w    = tid >> 6;          // wave id = N-tile 0..7
    const int l15  = lane & 15;
    const int g    = lane >> 4;
    const int col  = w * 16 + l15;      // this lane's output column
    const size_t rowBase = (size_t)blockIdx.x * 64;

    if (tid < 128) embC[tid] = teW[(size_t)(*task_id_p) * 128 + tid] + teB[tid];
    __syncthreads();

    auto LOADB = [&](const int mat, const int ks, short8& BH, short8& BL) {
        const u16* p = wsB + (size_t)(((mat * 4 + ks) * 8 + w) * 1024) + lane * 8;
        FragU h, l;
        h.u = *reinterpret_cast<const u32x4*>(p);
        l.u = *reinterpret_cast<const u32x4*>(p + 512);
        BH = h.s; BL = l.s;
    };

    // =========== phase A: fused gating matmul + base layer 0 (one x pass) ===========
    f32x4 accE[4];        // gating acc per M-tile
    f32x4 M0[4][4];       // [module][Mt] layer-0 mids
    f32x4 NB[4][4];       // second mid buffer (dead until phase C)
#pragma unroll
    for (int Mt = 0; Mt < 4; ++Mt) {
#pragma unroll
        for (int q = 0; q < 4; ++q) accE[Mt][q] = 0.f;
#pragma unroll
        for (int m = 0; m < 4; ++m)
#pragma unroll
            for (int q = 0; q < 4; ++q) M0[m][Mt][q] = 0.f;
    }

#pragma unroll
    for (int ks = 0; ks < 4; ++ks) {
        // hoisted B-fragments for all 5 matrices of this k-slice (gating + 4 modules)
        short8 BH5[5], BL5[5];
#pragma unroll
        for (int m = 0; m < 5; ++m) LOADB(m, ks, BH5[m], BL5[m]);
        const f32x4 c0 = *reinterpret_cast<const f32x4*>(&embC[ks * 32 + g * 8]);
        const f32x4 c1 = *reinterpret_cast<const f32x4*>(&embC[ks * 32 + g * 8 + 4]);
#pragma unroll
        for (int Mt = 0; Mt < 4; ++Mt) {
            const float* xp = x + (rowBase + Mt * 16 + l15) * 128 + ks * 32 + g * 8;
            const f32x4 x0 = *reinterpret_cast<const f32x4*>(xp);
            const f32x4 x1 = *reinterpret_cast<const f32x4*>(xp + 4);
            float vr[8], vg[8];
#pragma unroll
            for (int q = 0; q < 4; ++q) {
                vr[q] = x0[q];  vr[4 + q] = x1[q];
                vg[q]     = fmaxf(c0[q] * x0[q], 0.f);
                vg[4 + q] = fmaxf(c1[q] * x1[q], 0.f);
            }
            short8 Xh, Xl, Gh, Gl;
            split8(vr, Xh, Xl); split8(vg, Gh, Gl);
            accE[Mt] = __builtin_amdgcn_mfma_f32_16x16x32_bf16(Gh, BH5[0], accE[Mt], 0, 0, 0);
            accE[Mt] = __builtin_amdgcn_mfma_f32_16x16x32_bf16(Gl, BH5[0], accE[Mt], 0, 0, 0);
            accE[Mt] = __builtin_amdgcn_mfma_f32_16x16x32_bf16(Gh, BL5[0], accE[Mt], 0, 0, 0);
#pragma unroll
            for (int m = 0; m < 4; ++m) {
                M0[m][Mt] = __builtin_amdgcn_mfma_f32_16x16x32_bf16(Xh, BH5[1 + m], M0[m][Mt], 0, 0, 0);
                M0[m][Mt] = __builtin_amdgcn_mfma_f32_16x16x32_bf16(Xl, BH5[1 + m], M0[m][Mt], 0, 0, 0);
                M0[m][Mt] = __builtin_amdgcn_mfma_f32_16x16x32_bf16(Xh, BL5[1 + m], M0[m][Mt], 0, 0, 0);
            }
        }
    }
    // epilogues: emb -> embsF (fp32); layer-0 bias into M0
    {
        const float gb = gfB[col];
#pragma unroll
        for (int Mt = 0; Mt < 4; ++Mt)
#pragma unroll
            for (int q = 0; q < 4; ++q)
                embsF[(Mt * 16 + g * 4 + q) * PBS + col] = accE[Mt][q] + gb;
    }
#pragma unroll
    for (int m = 0; m < 4; ++m) {
        const float bv = bB[m * 128 + col];
#pragma unroll
        for (int Mt = 0; Mt < 4; ++Mt)
#pragma unroll
            for (int q = 0; q < 4; ++q) M0[m][Mt][q] += bv;
    }
    __syncthreads();

    // =========== phase B: routing chain (fp32 VALU, 8 threads/row, intra-wave only) ===========
    {
        const int rr = tid >> 3, c8 = tid & 7;
        const float* eRow = embsF + rr * PBS;
        const float* vRow = vsF + rr * PBS;
        float* flRow = &flS[rr][0];

        auto GW2 = [&](const float* Arow, const float* W, const float* Wb,
                       const bool doRelu, float o[2]) {
            o[0] = Wb[2 * c8]; o[1] = Wb[2 * c8 + 1];
#pragma unroll 8
            for (int k = 0; k < 128; ++k) {
                float a = Arow[k];
                if (doRelu) a = fmaxf(a, 0.f);
                const float* wp = W + k * 16 + 2 * c8;
                o[0] = fmaf(a, wp[0], o[0]);
                o[1] = fmaf(a, wp[1], o[1]);
            }
        };
        auto SMAX2 = [&](const int li, const float o[2], float sm[2]) {
            float mx = fmaxf(o[0], o[1]);
            mx = fmaxf(mx, __shfl_xor(mx, 1));
            const float e0 = expf(o[0] - mx), e1 = expf(o[1] - mx);
            float ss = e0 + e1;
            ss += __shfl_xor(ss, 1);
            const float inv = 1.f / ss;
            sm[0] = e0 * inv; sm[1] = e1 * inv;
            smT[li][2 * c8][rr] = sm[0];
            smT[li][2 * c8 + 1][rr] = sm[1];
        };
        auto CONDM = [&](const int K, const float* W, const float* Wb, f32x4 co[4]) {
#pragma unroll
            for (int j4 = 0; j4 < 4; ++j4)
                co[j4] = *reinterpret_cast<const f32x4*>(Wb + c8 * 16 + 4 * j4);
            for (int k = 0; k < K; ++k) {
                const float a = fmaxf(flRow[k], 0.f);
                const float* wp = W + k * 128 + c8 * 16;
#pragma unroll
                for (int j4 = 0; j4 < 4; ++j4) {
                    const f32x4 wq = *reinterpret_cast<const f32x4*>(wp + 4 * j4);
#pragma unroll
                    for (int q = 0; q < 4; ++q) co[j4][q] = fmaf(a, wq[q], co[j4][q]);
                }
            }
        };
        auto EMUL = [&](const f32x4 co[4]) {   // vs = relu(cond * emb)
#pragma unroll
            for (int j4 = 0; j4 < 4; ++j4)
#pragma unroll
                for (int q = 0; q < 4; ++q) {
                    const int u = 4 * j4 + q;
                    vsF[rr * PBS + c8 * 16 + u] = fmaxf(co[j4][q] * eRow[c8 * 16 + u], 0.f);
                }
        };

        float o2[2], sm2[2];
        f32x4 co[4];
        GW2(eRow, gw0W, gw0B, true, o2);               // raw0 = relu(emb) @ gw0
        SMAX2(0, o2, sm2);
        flRow[2 * c8] = sm2[0]; flRow[2 * c8 + 1] = sm2[1];     // flats[0] = softmaxed
        CONDM(16, c1W, c1B, co); EMUL(co);
        GW2(vRow, gw1W, gw1B, false, o2);              // raw1
        flRow[16 + 2 * c8] = o2[0]; flRow[16 + 2 * c8 + 1] = o2[1];   // raw
        SMAX2(1, o2, sm2);
        CONDM(32, c2W, c2B, co); EMUL(co);
        GW2(vRow, gw2W, gw2B, false, o2);              // raw2
        flRow[32 + 2 * c8] = o2[0]; flRow[32 + 2 * c8 + 1] = o2[1];
        SMAX2(2, o2, sm2);
        CONDM(48, cLW, cLB, co); EMUL(co);
        if (c8 < 4) {                                  // last_w = softmax(cond @ lfW + lfB)
            float lacc = lfB[c8];
#pragma unroll 8
            for (int k = 0; k < 128; ++k) lacc = fmaf(vRow[k], lfW[k * 4 + c8], lacc);
            float m1 = fmaxf(lacc, __shfl_xor(lacc, 1));
            m1 = fmaxf(m1, __shfl_xor(m1, 2));
            const float ee = expf(lacc - m1);
            float ss = ee + __shfl_xor(ee, 1);
            ss += __shfl_xor(ss, 2);
            lwT[c8][rr] = ee / ss;
        }
    }
    __syncthreads();

    // =========== phase C: layers 1..3 (mix in C-layout regs -> split pairs in LDS -> MFMA) ===========
    auto MIXJ = [&](const int li, const int jj, const f32x4 (&MID)[4][4], u32* buf) {
#pragma unroll
        for (int Mt = 0; Mt < 4; ++Mt) {
            const f32x4 wv0 = *reinterpret_cast<const f32x4*>(&smT[li][jj * 4 + 0][Mt * 16 + g * 4]);
            const f32x4 wv1 = *reinterpret_cast<const f32x4*>(&smT[li][jj * 4 + 1][Mt * 16 + g * 4]);
            const f32x4 wv2 = *reinterpret_cast<const f32x4*>(&smT[li][jj * 4 + 2][Mt * 16 + g * 4]);
            const f32x4 wv3 = *reinterpret_cast<const f32x4*>(&smT[li][jj * 4 + 3][Mt * 16 + g * 4]);
            u32* bp = buf + (Mt * 16 + g * 4) * PBS + col;
#pragma unroll
            for (int q = 0; q < 4; ++q) {
                float v = MID[0][Mt][q] * wv0[q] + MID[1][Mt][q] * wv1[q]
                        + MID[2][Mt][q] * wv2[q] + MID[3][Mt][q] * wv3[q];
                v = fmaxf(v, 0.f);
                const u32 uu = __float_as_uint(v);
                const u32 hb = uu & 0xFFFF0000u;
                const u32 lb = __float_as_uint(v - __uint_as_float(hb)) + 0x8000u;
                bp[q * PBS] = (hb >> 16) | (lb & 0xFFFF0000u);   // low16=hi, high16=lo
            }
        }
    };
    auto MMJ = [&](const int mat, const u32* buf, f32x4 (&ACC)[4]) {
#pragma unroll
        for (int Mt = 0; Mt < 4; ++Mt)
#pragma unroll
            for (int q = 0; q < 4; ++q) ACC[Mt][q] = 0.f;
#pragma unroll
        for (int ks = 0; ks < 4; ++ks) {
            short8 BH, BL; LOADB(mat, ks, BH, BL);
#pragma unroll
            for (int Mt = 0; Mt < 4; ++Mt) {
                const u32* ap = buf + (Mt * 16 + l15) * PBS + ks * 32 + g * 8;
                const u32x4 a0 = *reinterpret_cast<const u32x4*>(ap);
                const u32x4 a1 = *reinterpret_cast<const u32x4*>(ap + 4);
                FragU h, l;
                h.u[0] = (a0[0] & 0xFFFFu) | (a0[1] << 16);
                h.u[1] = (a0[2] & 0xFFFFu) | (a0[3] << 16);
                h.u[2] = (a1[0] & 0xFFFFu) | (a1[1] << 16);
                h.u[3] = (a1[2] & 0xFFFFu) | (a1[3] << 16);
                l.u[0] = (a0[0] >> 16) | (a0[1] & 0xFFFF0000u);
                l.u[1] = (a0[2] >> 16) | (a0[3] & 0xFFFF0000u);
                l.u[2] = (a1[0] >> 16) | (a1[1] & 0xFFFF0000u);
                l.u[3] = (a1[2] >> 16) | (a1[3] & 0xFFFF0000u);
                ACC[Mt] = __builtin_amdgcn_mfma_f32_16x16x32_bf16(h.s, BH, ACC[Mt], 0, 0, 0);
                ACC[Mt] = __builtin_amdgcn_mfma_f32_16x16x32_bf16(l.s, BH, ACC[Mt], 0, 0, 0);
                ACC[Mt] = __builtin_amdgcn_mfma_f32_16x16x32_bf16(h.s, BL, ACC[Mt], 0, 0, 0);
            }
        }
        const float bv = bB[(size_t)(mat - 1) * 128 + col];
#pragma unroll
        for (int Mt = 0; Mt < 4; ++Mt)
#pragma unroll
            for (int q = 0; q < 4; ++q) ACC[Mt][q] += bv;
    };

    u32* PB0 = &pairBuf[0][0];
    u32* PB1 = &pairBuf[1][0];

    // layer 1: mid0=M0 -> mid1=NB (mats 5..8)
    MIXJ(0, 0, M0, PB0); MIXJ(0, 1, M0, PB1); __syncthreads();
    MMJ(5, PB0, NB[0]);  MMJ(6, PB1, NB[1]);  __syncthreads();
    MIXJ(0, 2, M0, PB0); MIXJ(0, 3, M0, PB1); __syncthreads();
    MMJ(7, PB0, NB[2]);  MMJ(8, PB1, NB[3]);  __syncthreads();
    // layer 2: mid1=NB -> mid2=M0 (mats 9..12)
    MIXJ(1, 0, NB, PB0); MIXJ(1, 1, NB, PB1); __syncthreads();
    MMJ(9, PB0, M0[0]);  MMJ(10, PB1, M0[1]); __syncthreads();
    MIXJ(1, 2, NB, PB0); MIXJ(1, 3, NB, PB1); __syncthreads();
    MMJ(11, PB0, M0[2]); MMJ(12, PB1, M0[3]); __syncthreads();
    // layer 3: mid2=M0 -> mid3=NB (mats 13..16)
    MIXJ(2, 0, M0, PB0); MIXJ(2, 1, M0, PB1); __syncthreads();
    MMJ(13, PB0, NB[0]); MMJ(14, PB1, NB[1]); __syncthreads();
    MIXJ(2, 2, M0, PB0); MIXJ(2, 3, M0, PB1); __syncthreads();
    MMJ(15, PB0, NB[2]); MMJ(16, PB1, NB[3]);

    // =========== output: out = sum_j mid3_j * last_w_j ===========
#pragma unroll
    for (int Mt = 0; Mt < 4; ++Mt) {
        const f32x4 lw0 = *reinterpret_cast<const f32x4*>(&lwT[0][Mt * 16 + g * 4]);
        const f32x4 lw1 = *reinterpret_cast<const f32x4*>(&lwT[1][Mt * 16 + g * 4]);
        const f32x4 lw2 = *reinterpret_cast<const f32x4*>(&lwT[2][Mt * 16 + g * 4]);
        const f32x4 lw3 = *reinterpret_cast<const f32x4*>(&lwT[3][Mt * 16 + g * 4]);
#pragma unroll
        for (int q = 0; q < 4; ++q) {
            const float o = NB[0][Mt][q] * lw0[q] + NB[1][Mt][q] * lw1[q]
                          + NB[2][Mt][q] * lw2[q] + NB[3][Mt][q] * lw3[q];
            out[(rowBase + Mt * 16 + g * 4 + q) * 128 + col] = o;
        }
    }
}

extern "C" void kernel_launch(void* const* d_in, const int* in_sizes, int n_in,
                              void* d_out, int out_size, void* d_ws, size_t ws_size,
                              hipStream_t stream) {
    const float* x    = (const float*)d_in[0];
    const int*   tsk  = (const int*)  d_in[1];
    const float* teW  = (const float*)d_in[2];
    const float* teB  = (const float*)d_in[3];
    const float* gfW  = (const float*)d_in[4];
    const float* gfB  = (const float*)d_in[5];
    const float* gw0W = (const float*)d_in[6];
    const float* gw0B = (const float*)d_in[7];
    const float* c1W  = (const float*)d_in[8];
    const float* c1B  = (const float*)d_in[9];
    const float* gw1W = (const float*)d_in[10];
    const float* gw1B = (const float*)d_in[11];
    const float* c2W  = (const float*)d_in[12];
    const float* c2B  = (const float*)d_in[13];
    const float* gw2W = (const float*)d_in[14];
    const float* gw2B = (const float*)d_in[15];
    const float* cLW  = (const float*)d_in[16];
    const float* cLB  = (const float*)d_in[17];
    const float* lfW  = (const float*)d_in[18];
    const float* lfB  = (const float*)d_in[19];
    const float* bW   = (const float*)d_in[20];
    const float* bB   = (const float*)d_in[21];
    float* out = (float*)d_out;
    u16* wsB = (u16*)d_ws;     // needs 17*4*8*1024*2 B = 1,114,112 B

    const int Bn = in_sizes[0] / 128;          // 262144 rows
    prep_weights<<<(NMAT * 4 * 8 * 64 + 255) / 256, 256, 0, stream>>>(gfW, bW, wsB);
    softmod_mfma<<<Bn / 64, 512, 0, stream>>>(x, tsk, teW, teB, gfB,
                                              gw0W, gw0B, c1W, c1B, gw1W, gw1B,
                                              c2W, c2B, gw2W, gw2B, cLW, cLB,
                                              lfW, lfB, bB, wsB, out);
}